// Round 18
// baseline (290.121 us; speedup 1.0000x reference)
//
#include <hip/hip_runtime.h>
#include <hip/hip_fp16.h>

#define BB 4
#define NN 256
#define CC 256
#define HH 96
#define WW 128
#define P0 (HH*WW)        // 12288
#define TOTPOS 16320      // 12288 + 3072 + 768 + 192 = 255*64

// k_fuse strip geometry: 16 rows x 64 cols (R11/R16 champion)
#define SH 16
#define SW 64
#define CTH 20
#define CTW 68
#define HMH 18
#define HMW 66

typedef _Float16 f16x4 __attribute__((ext_vector_type(4)));
typedef _Float16 f16x8 __attribute__((ext_vector_type(8)));
typedef _Float16 h2    __attribute__((ext_vector_type(2)));
typedef float    f32x4 __attribute__((ext_vector_type(4)));

#if defined(__has_builtin)
#if __has_builtin(__builtin_amdgcn_fdot2)
#define FDOT2(a,b,c) __builtin_amdgcn_fdot2((a),(b),(c),false)
#endif
#endif
#ifndef FDOT2
#define FDOT2(a,b,c) ((c) + (float)(a)[0]*(float)(b)[0] + (float)(a)[1]*(float)(b)[1])
#endif

union F4U { f16x4 v; uint2 u; };
union F8U { f16x8 v; uint4 u; h2 h[4]; };

// hm swizzle — HW-proven (R5/R8)
__device__ __forceinline__ int hm_swz(int hx) {
    return (hx & 0xC) << 2;
}

// -------------------- K0: weight fragment prep (once, 2KB) --------------------
__global__ __launch_bounds__(64) void k_prep(const float* __restrict__ w1,
                                             _Float16* __restrict__ bfT) {
    int lane = threadIdx.x;
    int oc = lane & 15, og = lane >> 4;
    f16x8 bf0, bf1;
    #pragma unroll
    for (int e = 0; e < 8; ++e) {
        int k0 = og * 8 + e;
        bf0[e] = (_Float16)w1[oc * 36 + (k0 & 3) * 9 + (k0 >> 2)];
        int k1 = 32 + og * 8 + e;
        int kk1 = k1 >> 2;
        bf1[e] = (kk1 <= 8) ? (_Float16)w1[oc * 36 + (k1 & 3) * 9 + kk1] : (_Float16)0.f;
    }
    *(f16x8*)(bfT + lane * 16)     = bf0;
    *(f16x8*)(bfT + lane * 16 + 8) = bf1;
}

// -------------------- K1: normalize q rows -> f16 --------------------
__global__ __launch_bounds__(256) void k_qnorm(const float* __restrict__ q,
                                               _Float16* __restrict__ qn16) {
    int wid = blockIdx.x * 4 + (threadIdx.x >> 6);
    int lane = threadIdx.x & 63;
    const float4* src = (const float4*)(q + (size_t)wid * CC);
    float4 v = src[lane];
    float ss = v.x*v.x + v.y*v.y + v.z*v.z + v.w*v.w;
    #pragma unroll
    for (int off = 32; off > 0; off >>= 1) ss += __shfl_xor(ss, off, 64);
    float inv = 1.0f / fmaxf(sqrtf(ss), 1e-12f);
    f16x4 o;
    o[0] = (_Float16)(v.x*inv); o[1] = (_Float16)(v.y*inv);
    o[2] = (_Float16)(v.z*inv); o[3] = (_Float16)(v.w*inv);
    *(f16x4*)(qn16 + (size_t)wid * CC + lane * 4) = o;
}

// -------------------- K2: single-pass hierarchical pool + channel-norm (R16 proven) ----
__global__ __launch_bounds__(256) void k_pool_norm(const float* __restrict__ f,
                                                   _Float16* __restrict__ flnT) {
    __shared__ _Float16 vals[64][258];
    __shared__ _Float16 pooled[21][258];
    __shared__ float part_ss[256];
    __shared__ float inv_norm[85];
    int b = blockIdx.y;
    int tile = blockIdx.x;                 // 0..191 (12y x 16x)
    int ty = tile >> 4, tx = tile & 15;
    int c = threadIdx.x;

    const float* fb = f + ((size_t)b * P0) * CC + c;
    #pragma unroll 4
    for (int p = 0; p < 64; ++p) {
        int py = p >> 3, px = p & 7;
        int ip = (ty * 8 + py) * WW + tx * 8 + px;
        vals[p][c] = (_Float16)fb[(size_t)ip * CC];
    }
    __syncthreads();

    #pragma unroll
    for (int p1 = 0; p1 < 16; ++p1) {
        int py = p1 >> 2, px = p1 & 3;
        float s = (float)vals[(2*py)*8 + 2*px][c]     + (float)vals[(2*py)*8 + 2*px + 1][c]
                + (float)vals[(2*py+1)*8 + 2*px][c]   + (float)vals[(2*py+1)*8 + 2*px + 1][c];
        pooled[p1][c] = (_Float16)(s * 0.25f);
    }
    #pragma unroll
    for (int p2 = 0; p2 < 4; ++p2) {
        int py = p2 >> 1, px = p2 & 1;
        float s = (float)pooled[(2*py)*4 + 2*px][c]   + (float)pooled[(2*py)*4 + 2*px + 1][c]
                + (float)pooled[(2*py+1)*4 + 2*px][c] + (float)pooled[(2*py+1)*4 + 2*px + 1][c];
        pooled[16 + p2][c] = (_Float16)(s * 0.25f);
    }
    {
        float s = (float)pooled[16][c] + (float)pooled[17][c]
                + (float)pooled[18][c] + (float)pooled[19][c];
        pooled[20][c] = (_Float16)(s * 0.25f);
    }
    __syncthreads();

    {
        int pos = c >> 2, part = c & 3;
        float ss = 0.f;
        const _Float16* vp = &vals[pos][part * 64];
        #pragma unroll 8
        for (int j = 0; j < 64; ++j) { float v = (float)vp[j]; ss += v * v; }
        part_ss[c] = ss;
    }
    __syncthreads();
    if (c < 64) {
        float t = part_ss[4*c] + part_ss[4*c+1] + part_ss[4*c+2] + part_ss[4*c+3];
        inv_norm[c] = 1.0f / fmaxf(sqrtf(t), 1e-12f);
    }
    __syncthreads();
    {
        int pos = c >> 2, part = c & 3;
        float ss = 0.f;
        if (pos < 21) {
            const _Float16* vp = &pooled[pos][part * 64];
            #pragma unroll 8
            for (int j = 0; j < 64; ++j) { float v = (float)vp[j]; ss += v * v; }
        }
        part_ss[c] = ss;
    }
    __syncthreads();
    if (c < 21) {
        float t = part_ss[4*c] + part_ss[4*c+1] + part_ss[4*c+2] + part_ss[4*c+3];
        inv_norm[64 + c] = 1.0f / fmaxf(sqrtf(t), 1e-12f);
    }
    __syncthreads();

    size_t base = (size_t)b * TOTPOS;
    #pragma unroll 4
    for (int p = 0; p < 64; ++p) {
        int py = p >> 3, px = p & 7;
        int gp = (ty * 8 + py) * WW + tx * 8 + px;
        flnT[(base + gp) * CC + c] = (_Float16)((float)vals[p][c] * inv_norm[p]);
    }
    #pragma unroll
    for (int p1 = 0; p1 < 16; ++p1) {
        int py = p1 >> 2, px = p1 & 3;
        int gp = 12288 + (ty * 4 + py) * 64 + tx * 4 + px;
        flnT[(base + gp) * CC + c] = (_Float16)((float)pooled[p1][c] * inv_norm[64 + p1]);
    }
    #pragma unroll
    for (int p2 = 0; p2 < 4; ++p2) {
        int py = p2 >> 1, px = p2 & 1;
        int gp = 15360 + (ty * 2 + py) * 32 + tx * 2 + px;
        flnT[(base + gp) * CC + c] = (_Float16)((float)pooled[16 + p2][c] * inv_norm[80 + p2]);
    }
    {
        int gp = 16128 + ty * 16 + tx;
        flnT[(base + gp) * CC + c] = (_Float16)((float)pooled[20][c] * inv_norm[84]);
    }
}

// -------------------- K3: MFMA GEMM -> f16 output (proven R12/R13/R14) --------------------
__global__ __launch_bounds__(256, 4) void k_gemm(const _Float16* __restrict__ qn16,
                                                 const _Float16* __restrict__ flnT,
                                                 _Float16* __restrict__ cws16) {
    int b = blockIdx.z;
    int wv = threadIdx.x >> 6, lane = threadIdx.x & 63;
    int m0 = blockIdx.y * 64 + (wv >> 1) * 32;
    int p0 = blockIdx.x * 64 + (wv & 1) * 32;
    int r = lane & 15, og = lane >> 4;

    const f16x8* A0p = (const f16x8*)(qn16 + ((size_t)(b * NN + m0 + r)) * CC) + og;
    const f16x8* A1p = (const f16x8*)(qn16 + ((size_t)(b * NN + m0 + 16 + r)) * CC) + og;
    const f16x8* B0p = (const f16x8*)(flnT + ((size_t)b * TOTPOS + p0 + r) * CC) + og;
    const f16x8* B1p = (const f16x8*)(flnT + ((size_t)b * TOTPOS + p0 + 16 + r) * CC) + og;

    f32x4 acc00 = {0,0,0,0}, acc01 = {0,0,0,0}, acc10 = {0,0,0,0}, acc11 = {0,0,0,0};
    #pragma unroll 4
    for (int ko = 0; ko < 8; ++ko) {
        f16x8 a0 = A0p[ko * 4];
        f16x8 a1 = A1p[ko * 4];
        f16x8 b0 = B0p[ko * 4];
        f16x8 b1 = B1p[ko * 4];
        acc00 = __builtin_amdgcn_mfma_f32_16x16x32_f16(a0, b0, acc00, 0, 0, 0);
        acc01 = __builtin_amdgcn_mfma_f32_16x16x32_f16(a0, b1, acc01, 0, 0, 0);
        acc10 = __builtin_amdgcn_mfma_f32_16x16x32_f16(a1, b0, acc10, 0, 0, 0);
        acc11 = __builtin_amdgcn_mfma_f32_16x16x32_f16(a1, b1, acc11, 0, 0, 0);
    }
    size_t rowBase = (size_t)(b * NN + m0 + og * 4) * TOTPOS;
    #pragma unroll
    for (int rr = 0; rr < 4; ++rr) {
        size_t ro0 = rowBase + (size_t)rr * TOTPOS;
        size_t ro1 = ro0 + (size_t)16 * TOTPOS;
        cws16[ro0 + p0 + r]      = (_Float16)acc00[rr];
        cws16[ro0 + p0 + 16 + r] = (_Float16)acc01[rr];
        cws16[ro1 + p0 + r]      = (_Float16)acc10[rr];
        cws16[ro1 + p0 + 16 + r] = (_Float16)acc11[rr];
    }
}

// -------------------- K4: R16 champion k_fuse; ONLY dtype of cws reads changed ------
__global__ __launch_bounds__(512, 6) void k_fuse(const _Float16* __restrict__ cws16,
                                                 const _Float16* __restrict__ bfT,
                                                 const float* __restrict__ w2,
                                                 float* __restrict__ out) {
    __shared__ _Float16 cT[CTH * CTW * 4];     // 10880 B
    __shared__ _Float16 hm[HMH * HMW * 16];    // 38016 B
    __shared__ h2 w2h2[72];
    __shared__ int   xt01[3][CTW];
    __shared__ float xttx[3][CTW];
    __shared__ int   yt01[3][CTH];
    __shared__ float ytty[3][CTH];
    int img   = blockIdx.y;
    int strip = blockIdx.x;
    int y0 = (strip >> 1) * SH;
    int x0 = (strip & 1) * SW;
    int tid = threadIdx.x;
    int lane = tid & 63, wv = tid >> 6;        // 8 waves
    int oc = lane & 15, og = lane >> 4;
    const _Float16* cb = cws16 + (size_t)img * TOTPOS;

    if (tid < 72) {
        int tap = tid >> 3, j = tid & 7;
        h2 w; w[0] = (_Float16)w2[(2 * j) * 9 + tap];
        w[1] = (_Float16)w2[(2 * j + 1) * 9 + tap];
        w2h2[tid] = w;
    }
    for (int i = tid; i < 3 * CTW; i += 512) {
        int l = i / CTW + 1, rx = i - (l - 1) * CTW;
        int wl = WW >> l;
        float invk = (l == 1) ? 0.5f : (l == 2) ? 0.25f : 0.125f;
        float fx = ((x0 + rx - 2) + 0.5f) * invk - 0.5f;
        float x0f = floorf(fx);
        int ix = (int)x0f;
        int x1 = min(ix + 1, wl - 1); if (x1 < 0) x1 = 0;
        int xc = min(max(ix, 0), wl - 1);
        xt01[l - 1][rx] = xc | (x1 << 16);
        xttx[l - 1][rx] = fx - x0f;
    }
    if (tid < 3 * CTH) {
        int l = tid / CTH + 1, ry = tid - (l - 1) * CTH;
        int hl = HH >> l;
        float invk = (l == 1) ? 0.5f : (l == 2) ? 0.25f : 0.125f;
        float fy = ((y0 + ry - 2) + 0.5f) * invk - 0.5f;
        float y0f = floorf(fy);
        int iy = (int)y0f;
        int y1 = min(iy + 1, hl - 1); if (y1 < 0) y1 = 0;
        int yc = min(max(iy, 0), hl - 1);
        yt01[l - 1][ry] = yc | (y1 << 16);
        ytty[l - 1][ry] = fy - y0f;
    }

    f16x8 bf0 = *(const f16x8*)(bfT + lane * 16);
    f16x8 bf1 = *(const f16x8*)(bfT + lane * 16 + 8);
    int ofs0, ofs1, ofs8;
    {
        int kk0 = 2 * og,     ky0 = kk0 / 3, kx0 = kk0 - ky0 * 3;
        int kk1 = 2 * og + 1, ky1 = kk1 / 3, kx1 = kk1 - ky1 * 3;
        ofs0 = (ky0 * CTW + kx0 + 1 + oc) * 4;
        ofs1 = (ky1 * CTW + kx1 + 1 + oc) * 4;
        ofs8 = (2 * CTW + 2 + 1 + oc) * 4;
    }
    {
        uint4 z; z.x = z.y = z.z = z.w = 0u;
        uint4* hp = (uint4*)hm;
        for (int i = tid; i < (HMH * HMW * 16 * 2) / 16; i += 512) hp[i] = z;
    }
    __syncthreads();

    for (int i = tid; i < CTH * CTW; i += 512) {
        int ry = i / CTW, rx = i - ry * CTW;
        int gy = y0 + ry - 2, gx = x0 + rx - 2;
        f16x4 vv = {(_Float16)0.f, (_Float16)0.f, (_Float16)0.f, (_Float16)0.f};
        if ((unsigned)gy < HH && (unsigned)gx < WW) {
            vv[0] = cb[gy * WW + gx];
            #pragma unroll
            for (int l = 1; l < 4; ++l) {
                int wl = WW >> l;
                int lvlOff = (l == 1) ? 12288 : (l == 2) ? 15360 : 16128;
                int p01 = xt01[l - 1][rx];
                float tx = xttx[l - 1][rx];
                int q01 = yt01[l - 1][ry];
                float ty = ytty[l - 1][ry];
                int xa = p01 & 0xFFFF, xb = p01 >> 16;
                int ya = q01 & 0xFFFF, yb = q01 >> 16;
                const _Float16* r0 = cb + lvlOff + ya * wl;
                const _Float16* r1 = cb + lvlOff + yb * wl;
                float v00 = (float)r0[xa], v01 = (float)r0[xb];
                float v10 = (float)r1[xa], v11 = (float)r1[xb];
                float top = v00 + tx * (v01 - v00);
                float bot = v10 + tx * (v11 - v10);
                vv[l] = (_Float16)(top + ty * (bot - top));
            }
        }
        *(f16x4*)&cT[i * 4] = vv;
    }
    __syncthreads();

    for (int it = 0; it < 12; ++it) {
        int t = it * 8 + wv;
        if (t >= 90) break;
        int hyr = t / 5, xg = t - hyr * 5;
        if ((unsigned)(y0 + hyr - 1) >= (unsigned)HH) continue;
        int xb = (xg < 4) ? xg * 16 - 1 : 49;
        int base = (hyr * CTW + xb) * 4;
        F4U a00, a01, a8;
        a00.v = *(const f16x4*)&cT[base + ofs0];
        a01.v = *(const f16x4*)&cT[base + ofs1];
        a8.v  = *(const f16x4*)&cT[base + ofs8];
        F8U A0, A1;
        A0.u.x = a00.u.x; A0.u.y = a00.u.y; A0.u.z = a01.u.x; A0.u.w = a01.u.y;
        A1.u.x = a8.u.x;  A1.u.y = a8.u.y;  A1.u.z = a8.u.x;  A1.u.w = a8.u.y;
        f32x4 acc = {0.f, 0.f, 0.f, 0.f};
        acc = __builtin_amdgcn_mfma_f32_16x16x32_f16(A0.v, bf0, acc, 0, 0, 0);
        acc = __builtin_amdgcn_mfma_f32_16x16x32_f16(A1.v, bf1, acc, 0, 0, 0);
        int hxb = xb + og * 4 + 1;
        #pragma unroll
        for (int r = 0; r < 4; ++r) {
            int hx = hxb + r;
            int imgx = x0 + hx - 1;
            bool st = ((unsigned)imgx < (unsigned)WW) && (xg < 4 || hx >= 64);
            if (st) {
                int byt = ((hyr * HMW + hx) * 32 + oc * 2) ^ hm_swz(hx);
                *(_Float16*)((char*)hm + byt) = (_Float16)fmaxf(acc[r], 0.f);
            }
        }
    }
    __syncthreads();

    int row = tid >> 5, x2 = (tid & 31) * 2;
    int colof[4][2];
    #pragma unroll
    for (int c4 = 0; c4 < 4; ++c4) {
        int hx = x2 + c4;
        int sw = hm_swz(hx);
        colof[c4][0] = (hx * 32) ^ sw;
        colof[c4][1] = (hx * 32 + 16) ^ sw;
    }
    float a2[2] = {0.f, 0.f};
    #pragma unroll
    for (int r = 0; r < 3; ++r) {
        int rowb = (row + r) * (HMW * 32);
        h2 wrow[3][8];
        #pragma unroll
        for (int kx = 0; kx < 3; ++kx)
            #pragma unroll
            for (int j = 0; j < 8; ++j) wrow[kx][j] = w2h2[(r * 3 + kx) * 8 + j];
        F8U d[4][2];
        #pragma unroll
        for (int c4 = 0; c4 < 4; ++c4) {
            d[c4][0].v = *(const f16x8*)((const char*)hm + (rowb + colof[c4][0]));
            d[c4][1].v = *(const f16x8*)((const char*)hm + (rowb + colof[c4][1]));
        }
        #pragma unroll
        for (int q = 0; q < 2; ++q)
            #pragma unroll
            for (int kx = 0; kx < 3; ++kx) {
                #pragma unroll
                for (int j = 0; j < 4; ++j) {
                    a2[q] = FDOT2(d[q + kx][0].h[j], wrow[kx][j], a2[q]);
                    a2[q] = FDOT2(d[q + kx][1].h[j], wrow[kx][j + 4], a2[q]);
                }
            }
    }
    int gy = y0 + row, gx = x0 + x2;
    const h2 resh = *(const h2*)&cb[gy * WW + x2 + x0 - x0 + gx - gx + 0];  // see below
    // (explicit simple form:)
    float2 o;
    {
        const h2 rh = *(const h2*)&cb[gy * WW + gx];
        o.x = a2[0] + (float)rh[0];
        o.y = a2[1] + (float)rh[1];
    }
    (void)resh;
    *(float2*)&out[(size_t)img * P0 + gy * WW + gx] = o;
}

extern "C" void kernel_launch(void* const* d_in, const int* in_sizes, int n_in,
                              void* d_out, int out_size, void* d_ws, size_t ws_size,
                              hipStream_t stream) {
    const float* q  = (const float*)d_in[0];
    const float* f  = (const float*)d_in[1];
    const float* w1 = (const float*)d_in[2];
    const float* w2 = (const float*)d_in[3];
    float* out = (float*)d_out;

    _Float16* wsh   = (_Float16*)d_ws;
    _Float16* cws16 = wsh;                                        // B*N*TOTPOS
    _Float16* flnT  = cws16 + (size_t)BB * NN * TOTPOS;           // B*TOTPOS*C
    _Float16* qn16  = flnT + (size_t)BB * TOTPOS * CC;            // B*N*C
    _Float16* bfT   = qn16 + (size_t)BB * NN * CC;                // 1024

    hipLaunchKernelGGL(k_prep, dim3(1), dim3(64), 0, stream, w1, bfT);
    hipLaunchKernelGGL(k_qnorm, dim3(BB * NN / 4), dim3(256), 0, stream, q, qn16);
    hipLaunchKernelGGL(k_pool_norm, dim3(192, BB), dim3(256), 0, stream, f, flnT);
    hipLaunchKernelGGL(k_gemm, dim3(255, 4, BB), dim3(256), 0, stream, qn16, flnT, cws16);
    hipLaunchKernelGGL(k_fuse, dim3(12, BB * NN), dim3(512), 0, stream, cws16, bfT, w2, out);
}

// Round 20
// 286.524 us; speedup vs baseline: 1.0126x; 1.0126x over previous
//
#include <hip/hip_runtime.h>
#include <hip/hip_fp16.h>

#define BB 4
#define NN 256
#define CC 256
#define HH 96
#define WW 128
#define P0 (HH*WW)        // 12288
#define TOTPOS 16320      // 12288 + 3072 + 768 + 192 = 255*64

// k_fuse strip geometry: 16 rows x 64 cols (champion)
#define SH 16
#define SW 64
#define CTH 20
#define CTW 68
#define HMH 18
#define HMW 66

typedef _Float16 f16x4 __attribute__((ext_vector_type(4)));
typedef _Float16 f16x8 __attribute__((ext_vector_type(8)));
typedef _Float16 h2    __attribute__((ext_vector_type(2)));
typedef float    f32x4 __attribute__((ext_vector_type(4)));

#if defined(__has_builtin)
#if __has_builtin(__builtin_amdgcn_fdot2)
#define FDOT2(a,b,c) __builtin_amdgcn_fdot2((a),(b),(c),false)
#endif
#endif
#ifndef FDOT2
#define FDOT2(a,b,c) ((c) + (float)(a)[0]*(float)(b)[0] + (float)(a)[1]*(float)(b)[1])
#endif

union F4U { f16x4 v; uint2 u; };
union F8U { f16x8 v; uint4 u; h2 h[4]; };

// hm swizzle — HW-proven (R5/R8)
__device__ __forceinline__ int hm_swz(int hx) {
    return (hx & 0xC) << 2;
}

// -------------------- K0: weight fragment prep (once, 2KB) --------------------
__global__ __launch_bounds__(64) void k_prep(const float* __restrict__ w1,
                                             _Float16* __restrict__ bfT) {
    int lane = threadIdx.x;
    int oc = lane & 15, og = lane >> 4;
    f16x8 bf0, bf1;
    #pragma unroll
    for (int e = 0; e < 8; ++e) {
        int k0 = og * 8 + e;
        bf0[e] = (_Float16)w1[oc * 36 + (k0 & 3) * 9 + (k0 >> 2)];
        int k1 = 32 + og * 8 + e;
        int kk1 = k1 >> 2;
        bf1[e] = (kk1 <= 8) ? (_Float16)w1[oc * 36 + (k1 & 3) * 9 + kk1] : (_Float16)0.f;
    }
    *(f16x8*)(bfT + lane * 16)     = bf0;
    *(f16x8*)(bfT + lane * 16 + 8) = bf1;
}

// -------------------- K1: normalize q rows -> f16 --------------------
__global__ __launch_bounds__(256) void k_qnorm(const float* __restrict__ q,
                                               _Float16* __restrict__ qn16) {
    int wid = blockIdx.x * 4 + (threadIdx.x >> 6);
    int lane = threadIdx.x & 63;
    const float4* src = (const float4*)(q + (size_t)wid * CC);
    float4 v = src[lane];
    float ss = v.x*v.x + v.y*v.y + v.z*v.z + v.w*v.w;
    #pragma unroll
    for (int off = 32; off > 0; off >>= 1) ss += __shfl_xor(ss, off, 64);
    float inv = 1.0f / fmaxf(sqrtf(ss), 1e-12f);
    f16x4 o;
    o[0] = (_Float16)(v.x*inv); o[1] = (_Float16)(v.y*inv);
    o[2] = (_Float16)(v.z*inv); o[3] = (_Float16)(v.w*inv);
    *(f16x4*)(qn16 + (size_t)wid * CC + lane * 4) = o;
}

// -------------------- K2: single-pass hierarchical pool + channel-norm (R16 proven) ----
// Paranoid-sync: no shfl; LDS-scratch reductions; __syncthreads outside conditionals.
__global__ __launch_bounds__(256) void k_pool_norm(const float* __restrict__ f,
                                                   _Float16* __restrict__ flnT) {
    __shared__ _Float16 vals[64][258];
    __shared__ _Float16 pooled[21][258];
    __shared__ float part_ss[256];
    __shared__ float inv_norm[85];
    int b = blockIdx.y;
    int tile = blockIdx.x;                 // 0..191 (12y x 16x)
    int ty = tile >> 4, tx = tile & 15;
    int c = threadIdx.x;

    const float* fb = f + ((size_t)b * P0) * CC + c;
    #pragma unroll 4
    for (int p = 0; p < 64; ++p) {
        int py = p >> 3, px = p & 7;
        int ip = (ty * 8 + py) * WW + tx * 8 + px;
        vals[p][c] = (_Float16)fb[(size_t)ip * CC];
    }
    __syncthreads();

    #pragma unroll
    for (int p1 = 0; p1 < 16; ++p1) {
        int py = p1 >> 2, px = p1 & 3;
        float s = (float)vals[(2*py)*8 + 2*px][c]     + (float)vals[(2*py)*8 + 2*px + 1][c]
                + (float)vals[(2*py+1)*8 + 2*px][c]   + (float)vals[(2*py+1)*8 + 2*px + 1][c];
        pooled[p1][c] = (_Float16)(s * 0.25f);
    }
    #pragma unroll
    for (int p2 = 0; p2 < 4; ++p2) {
        int py = p2 >> 1, px = p2 & 1;
        float s = (float)pooled[(2*py)*4 + 2*px][c]   + (float)pooled[(2*py)*4 + 2*px + 1][c]
                + (float)pooled[(2*py+1)*4 + 2*px][c] + (float)pooled[(2*py+1)*4 + 2*px + 1][c];
        pooled[16 + p2][c] = (_Float16)(s * 0.25f);
    }
    {
        float s = (float)pooled[16][c] + (float)pooled[17][c]
                + (float)pooled[18][c] + (float)pooled[19][c];
        pooled[20][c] = (_Float16)(s * 0.25f);
    }
    __syncthreads();

    {
        int pos = c >> 2, part = c & 3;
        float ss = 0.f;
        const _Float16* vp = &vals[pos][part * 64];
        #pragma unroll 8
        for (int j = 0; j < 64; ++j) { float v = (float)vp[j]; ss += v * v; }
        part_ss[c] = ss;
    }
    __syncthreads();
    if (c < 64) {
        float t = part_ss[4*c] + part_ss[4*c+1] + part_ss[4*c+2] + part_ss[4*c+3];
        inv_norm[c] = 1.0f / fmaxf(sqrtf(t), 1e-12f);
    }
    __syncthreads();
    {
        int pos = c >> 2, part = c & 3;
        float ss = 0.f;
        if (pos < 21) {
            const _Float16* vp = &pooled[pos][part * 64];
            #pragma unroll 8
            for (int j = 0; j < 64; ++j) { float v = (float)vp[j]; ss += v * v; }
        }
        part_ss[c] = ss;
    }
    __syncthreads();
    if (c < 21) {
        float t = part_ss[4*c] + part_ss[4*c+1] + part_ss[4*c+2] + part_ss[4*c+3];
        inv_norm[64 + c] = 1.0f / fmaxf(sqrtf(t), 1e-12f);
    }
    __syncthreads();

    size_t base = (size_t)b * TOTPOS;
    #pragma unroll 4
    for (int p = 0; p < 64; ++p) {
        int py = p >> 3, px = p & 7;
        int gp = (ty * 8 + py) * WW + tx * 8 + px;
        flnT[(base + gp) * CC + c] = (_Float16)((float)vals[p][c] * inv_norm[p]);
    }
    #pragma unroll
    for (int p1 = 0; p1 < 16; ++p1) {
        int py = p1 >> 2, px = p1 & 3;
        int gp = 12288 + (ty * 4 + py) * 64 + tx * 4 + px;
        flnT[(base + gp) * CC + c] = (_Float16)((float)pooled[p1][c] * inv_norm[64 + p1]);
    }
    #pragma unroll
    for (int p2 = 0; p2 < 4; ++p2) {
        int py = p2 >> 1, px = p2 & 1;
        int gp = 15360 + (ty * 2 + py) * 32 + tx * 2 + px;
        flnT[(base + gp) * CC + c] = (_Float16)((float)pooled[16 + p2][c] * inv_norm[80 + p2]);
    }
    {
        int gp = 16128 + ty * 16 + tx;
        flnT[(base + gp) * CC + c] = (_Float16)((float)pooled[20][c] * inv_norm[84]);
    }
}

// -------------------- K3: MFMA GEMM (champion, fp32 out) --------------------
__global__ __launch_bounds__(256, 4) void k_gemm(const _Float16* __restrict__ qn16,
                                                 const _Float16* __restrict__ flnT,
                                                 float* __restrict__ cws) {
    int b = blockIdx.z;
    int wv = threadIdx.x >> 6, lane = threadIdx.x & 63;
    int m0 = blockIdx.y * 64 + (wv >> 1) * 32;
    int p0 = blockIdx.x * 64 + (wv & 1) * 32;
    int r = lane & 15, og = lane >> 4;

    const f16x8* A0p = (const f16x8*)(qn16 + ((size_t)(b * NN + m0 + r)) * CC) + og;
    const f16x8* A1p = (const f16x8*)(qn16 + ((size_t)(b * NN + m0 + 16 + r)) * CC) + og;
    const f16x8* B0p = (const f16x8*)(flnT + ((size_t)b * TOTPOS + p0 + r) * CC) + og;
    const f16x8* B1p = (const f16x8*)(flnT + ((size_t)b * TOTPOS + p0 + 16 + r) * CC) + og;

    f32x4 acc00 = {0,0,0,0}, acc01 = {0,0,0,0}, acc10 = {0,0,0,0}, acc11 = {0,0,0,0};
    #pragma unroll 4
    for (int ko = 0; ko < 8; ++ko) {
        f16x8 a0 = A0p[ko * 4];
        f16x8 a1 = A1p[ko * 4];
        f16x8 b0 = B0p[ko * 4];
        f16x8 b1 = B1p[ko * 4];
        acc00 = __builtin_amdgcn_mfma_f32_16x16x32_f16(a0, b0, acc00, 0, 0, 0);
        acc01 = __builtin_amdgcn_mfma_f32_16x16x32_f16(a0, b1, acc01, 0, 0, 0);
        acc10 = __builtin_amdgcn_mfma_f32_16x16x32_f16(a1, b0, acc10, 0, 0, 0);
        acc11 = __builtin_amdgcn_mfma_f32_16x16x32_f16(a1, b1, acc11, 0, 0, 0);
    }
    size_t rowBase = (size_t)(b * NN + m0 + og * 4) * TOTPOS;
    #pragma unroll
    for (int rr = 0; rr < 4; ++rr) {
        size_t ro0 = rowBase + (size_t)rr * TOTPOS;
        size_t ro1 = ro0 + (size_t)16 * TOTPOS;
        cws[ro0 + p0 + r]      = acc00[rr];
        cws[ro0 + p0 + 16 + r] = acc01[rr];
        cws[ro1 + p0 + r]      = acc10[rr];
        cws[ro1 + p0 + 16 + r] = acc11[rr];
    }
}

// -------------------- K4: champion k_fuse --------------------
__global__ __launch_bounds__(512, 6) void k_fuse(const float* __restrict__ cws,
                                                 const _Float16* __restrict__ bfT,
                                                 const float* __restrict__ w2,
                                                 float* __restrict__ out) {
    __shared__ _Float16 cT[CTH * CTW * 4];     // 10880 B
    __shared__ _Float16 hm[HMH * HMW * 16];    // 38016 B
    __shared__ h2 w2h2[72];
    __shared__ int   xt01[3][CTW];
    __shared__ float xttx[3][CTW];
    __shared__ int   yt01[3][CTH];
    __shared__ float ytty[3][CTH];
    int img   = blockIdx.y;
    int strip = blockIdx.x;
    int y0 = (strip >> 1) * SH;
    int x0 = (strip & 1) * SW;
    int tid = threadIdx.x;
    int lane = tid & 63, wv = tid >> 6;        // 8 waves
    int oc = lane & 15, og = lane >> 4;
    const float* cb = cws + (size_t)img * TOTPOS;

    if (tid < 72) {
        int tap = tid >> 3, j = tid & 7;
        h2 w; w[0] = (_Float16)w2[(2 * j) * 9 + tap];
        w[1] = (_Float16)w2[(2 * j + 1) * 9 + tap];
        w2h2[tid] = w;
    }
    for (int i = tid; i < 3 * CTW; i += 512) {
        int l = i / CTW + 1, rx = i - (l - 1) * CTW;
        int wl = WW >> l;
        float invk = (l == 1) ? 0.5f : (l == 2) ? 0.25f : 0.125f;
        float fx = ((x0 + rx - 2) + 0.5f) * invk - 0.5f;
        float x0f = floorf(fx);
        int ix = (int)x0f;
        int x1 = min(ix + 1, wl - 1); if (x1 < 0) x1 = 0;
        int xc = min(max(ix, 0), wl - 1);
        xt01[l - 1][rx] = xc | (x1 << 16);
        xttx[l - 1][rx] = fx - x0f;
    }
    if (tid < 3 * CTH) {
        int l = tid / CTH + 1, ry = tid - (l - 1) * CTH;
        int hl = HH >> l;
        float invk = (l == 1) ? 0.5f : (l == 2) ? 0.25f : 0.125f;
        float fy = ((y0 + ry - 2) + 0.5f) * invk - 0.5f;
        float y0f = floorf(fy);
        int iy = (int)y0f;
        int y1 = min(iy + 1, hl - 1); if (y1 < 0) y1 = 0;
        int yc = min(max(iy, 0), hl - 1);
        yt01[l - 1][ry] = yc | (y1 << 16);
        ytty[l - 1][ry] = fy - y0f;
    }

    f16x8 bf0 = *(const f16x8*)(bfT + lane * 16);
    f16x8 bf1 = *(const f16x8*)(bfT + lane * 16 + 8);
    int ofs0, ofs1, ofs8;
    {
        int kk0 = 2 * og,     ky0 = kk0 / 3, kx0 = kk0 - ky0 * 3;
        int kk1 = 2 * og + 1, ky1 = kk1 / 3, kx1 = kk1 - ky1 * 3;
        ofs0 = (ky0 * CTW + kx0 + 1 + oc) * 4;
        ofs1 = (ky1 * CTW + kx1 + 1 + oc) * 4;
        ofs8 = (2 * CTW + 2 + 1 + oc) * 4;
    }
    {
        uint4 z; z.x = z.y = z.z = z.w = 0u;
        uint4* hp = (uint4*)hm;
        for (int i = tid; i < (HMH * HMW * 16 * 2) / 16; i += 512) hp[i] = z;
    }
    __syncthreads();

    for (int i = tid; i < CTH * CTW; i += 512) {
        int ry = i / CTW, rx = i - ry * CTW;
        int gy = y0 + ry - 2, gx = x0 + rx - 2;
        f16x4 vv = {(_Float16)0.f, (_Float16)0.f, (_Float16)0.f, (_Float16)0.f};
        if ((unsigned)gy < HH && (unsigned)gx < WW) {
            vv[0] = (_Float16)cb[gy * WW + gx];
            #pragma unroll
            for (int l = 1; l < 4; ++l) {
                int wl = WW >> l;
                int lvlOff = (l == 1) ? 12288 : (l == 2) ? 15360 : 16128;
                int p01 = xt01[l - 1][rx];
                float tx = xttx[l - 1][rx];
                int q01 = yt01[l - 1][ry];
                float ty = ytty[l - 1][ry];
                int xa = p01 & 0xFFFF, xb = p01 >> 16;
                int ya = q01 & 0xFFFF, yb = q01 >> 16;
                const float* r0 = cb + lvlOff + ya * wl;
                const float* r1 = cb + lvlOff + yb * wl;
                float v00 = r0[xa], v01 = r0[xb];
                float v10 = r1[xa], v11 = r1[xb];
                float top = v00 + tx * (v01 - v00);
                float bot = v10 + tx * (v11 - v10);
                vv[l] = (_Float16)(top + ty * (bot - top));
            }
        }
        *(f16x4*)&cT[i * 4] = vv;
    }
    __syncthreads();

    for (int it = 0; it < 12; ++it) {
        int t = it * 8 + wv;
        if (t >= 90) break;
        int hyr = t / 5, xg = t - hyr * 5;
        if ((unsigned)(y0 + hyr - 1) >= (unsigned)HH) continue;
        int xb = (xg < 4) ? xg * 16 - 1 : 49;
        int base = (hyr * CTW + xb) * 4;
        F4U a00, a01, a8;
        a00.v = *(const f16x4*)&cT[base + ofs0];
        a01.v = *(const f16x4*)&cT[base + ofs1];
        a8.v  = *(const f16x4*)&cT[base + ofs8];
        F8U A0, A1;
        A0.u.x = a00.u.x; A0.u.y = a00.u.y; A0.u.z = a01.u.x; A0.u.w = a01.u.y;
        A1.u.x = a8.u.x;  A1.u.y = a8.u.y;  A1.u.z = a8.u.x;  A1.u.w = a8.u.y;
        f32x4 acc = {0.f, 0.f, 0.f, 0.f};
        acc = __builtin_amdgcn_mfma_f32_16x16x32_f16(A0.v, bf0, acc, 0, 0, 0);
        acc = __builtin_amdgcn_mfma_f32_16x16x32_f16(A1.v, bf1, acc, 0, 0, 0);
        int hxb = xb + og * 4 + 1;
        #pragma unroll
        for (int r = 0; r < 4; ++r) {
            int hx = hxb + r;
            int imgx = x0 + hx - 1;
            bool st = ((unsigned)imgx < (unsigned)WW) && (xg < 4 || hx >= 64);
            if (st) {
                int byt = ((hyr * HMW + hx) * 32 + oc * 2) ^ hm_swz(hx);
                *(_Float16*)((char*)hm + byt) = (_Float16)fmaxf(acc[r], 0.f);
            }
        }
    }
    __syncthreads();

    int row = tid >> 5, x2 = (tid & 31) * 2;
    int colof[4][2];
    #pragma unroll
    for (int c4 = 0; c4 < 4; ++c4) {
        int hx = x2 + c4;
        int sw = hm_swz(hx);
        colof[c4][0] = (hx * 32) ^ sw;
        colof[c4][1] = (hx * 32 + 16) ^ sw;
    }
    float a2[2] = {0.f, 0.f};
    #pragma unroll
    for (int r = 0; r < 3; ++r) {
        int rowb = (row + r) * (HMW * 32);
        h2 wrow[3][8];
        #pragma unroll
        for (int kx = 0; kx < 3; ++kx)
            #pragma unroll
            for (int j = 0; j < 8; ++j) wrow[kx][j] = w2h2[(r * 3 + kx) * 8 + j];
        F8U d[4][2];
        #pragma unroll
        for (int c4 = 0; c4 < 4; ++c4) {
            d[c4][0].v = *(const f16x8*)((const char*)hm + (rowb + colof[c4][0]));
            d[c4][1].v = *(const f16x8*)((const char*)hm + (rowb + colof[c4][1]));
        }
        #pragma unroll
        for (int q = 0; q < 2; ++q)
            #pragma unroll
            for (int kx = 0; kx < 3; ++kx) {
                #pragma unroll
                for (int j = 0; j < 4; ++j) {
                    a2[q] = FDOT2(d[q + kx][0].h[j], wrow[kx][j], a2[q]);
                    a2[q] = FDOT2(d[q + kx][1].h[j], wrow[kx][j + 4], a2[q]);
                }
            }
    }
    int gy = y0 + row, gx = x0 + x2;
    const float2 res = *(const float2*)&cb[gy * WW + gx];
    float2 o;
    o.x = a2[0] + res.x; o.y = a2[1] + res.y;
    *(float2*)&out[(size_t)img * P0 + gy * WW + gx] = o;
}

extern "C" void kernel_launch(void* const* d_in, const int* in_sizes, int n_in,
                              void* d_out, int out_size, void* d_ws, size_t ws_size,
                              hipStream_t stream) {
    const float* q  = (const float*)d_in[0];
    const float* f  = (const float*)d_in[1];
    const float* w1 = (const float*)d_in[2];
    const float* w2 = (const float*)d_in[3];
    float* out = (float*)d_out;

    float* cws = (float*)d_ws;                                    // B*N*TOTPOS fp32
    _Float16* flnT = (_Float16*)(cws + (size_t)BB * NN * TOTPOS); // B*TOTPOS*C f16
    _Float16* qn16 = flnT + (size_t)BB * TOTPOS * CC;             // B*N*C f16
    _Float16* bfT  = qn16 + (size_t)BB * NN * CC;                 // 1024

    hipLaunchKernelGGL(k_prep, dim3(1), dim3(64), 0, stream, w1, bfT);
    hipLaunchKernelGGL(k_qnorm, dim3(BB * NN / 4), dim3(256), 0, stream, q, qn16);
    hipLaunchKernelGGL(k_pool_norm, dim3(192, BB), dim3(256), 0, stream, f, flnT);
    hipLaunchKernelGGL(k_gemm, dim3(255, 4, BB), dim3(256), 0, stream, qn16, flnT, cws);
    hipLaunchKernelGGL(k_fuse, dim3(12, BB * NN), dim3(512), 0, stream, cws, bfT, w2, out);
}